// Round 1
// baseline (1864.496 us; speedup 1.0000x reference)
//
#include <hip/hip_runtime.h>
#include <math.h>

// ---------------------------------------------------------------------------
// TopK graph classifier: 3x (GraphConv -> TopKPool -> readout) + 2x KNN + MLP
// Sizes are static (from reference): N0=65536,C_IN=64,H=128,E0=524288
// pooled sizes 32768/16384/8192; knn k=6 then k=8.
// ---------------------------------------------------------------------------

namespace {

constexpr int N0 = 65536;
constexpr int C0 = 64;
constexpr int H  = 128;
constexpr int E0 = 524288;
constexpr int N1 = 32768;   // ceil(0.5*N0)
constexpr int N2 = 16384;
constexpr int N3 = 8192;
constexpr int KNN_P = 8;    // partitions per query for knn parallelism

// ---------------- utility ----------------
__global__ void fill_zero_kernel(float* __restrict__ p, int n) {
  int i = blockIdx.x * blockDim.x + threadIdx.x;
  if (i < n) p[i] = 0.f;
}

// ---------------- conv0 aggregation: segment_sum over random edges ----------
// wave-per-edge: lane f handles feature f (C0=64 == wavefront)
__global__ void scatter_add_kernel(const float* __restrict__ x,
                                   const int* __restrict__ src,
                                   const int* __restrict__ dst,
                                   float* __restrict__ agg) {
  int gid = blockIdx.x * blockDim.x + threadIdx.x;
  int e = gid >> 6;
  int f = gid & 63;
  if (e < E0) {
    atomicAdd(&agg[(size_t)dst[e] * C0 + f], x[(size_t)src[e] * C0 + f]);
  }
}

// ---------------- graph conv: out = relu(agg@Wrel + brel + x@Wroot) ---------
// 128 threads (one per output channel), R rows per block, rows staged in LDS.
template<int C, int R>
__global__ void conv_kernel(const float* __restrict__ agg,
                            const float* __restrict__ x,
                            const float* __restrict__ Wrel,
                            const float* __restrict__ brel,
                            const float* __restrict__ Wroot,
                            float* __restrict__ out) {
  __shared__ float sa[R][C];
  __shared__ float sx[R][C];
  int base = blockIdx.x * R;
  int o = threadIdx.x;  // 0..127
  for (int idx = threadIdx.x; idx < R * C; idx += 128) {
    int r = idx / C, c = idx - r * C;
    sa[r][c] = agg[(size_t)(base + r) * C + c];
    sx[r][c] = x[(size_t)(base + r) * C + c];
  }
  __syncthreads();
  float acc[R];
  float b = brel[o];
#pragma unroll
  for (int r = 0; r < R; ++r) acc[r] = b;
  for (int c = 0; c < C; ++c) {
    float wr = Wrel[c * H + o];
    float wo = Wroot[c * H + o];
#pragma unroll
    for (int r = 0; r < R; ++r) acc[r] += sa[r][c] * wr + sx[r][c] * wo;
  }
#pragma unroll
  for (int r = 0; r < R; ++r) out[(size_t)(base + r) * H + o] = fmaxf(acc[r], 0.f);
}

// ---------------- pooling scores: tanh(x.pw/||pw||), + radix-sortable key ---
// one wave per node
__global__ void score_kernel(const float* __restrict__ xin,
                             const float* __restrict__ pw,
                             float* __restrict__ score,
                             unsigned* __restrict__ key, int N) {
  int gid = blockIdx.x * blockDim.x + threadIdx.x;
  int wid = gid >> 6;
  int lane = threadIdx.x & 63;
  if (wid >= N) return;
  float w0 = pw[lane], w1 = pw[64 + lane];
  float x0 = xin[(size_t)wid * H + lane], x1 = xin[(size_t)wid * H + 64 + lane];
  float dot = x0 * w0 + x1 * w1;
  float nw = w0 * w0 + w1 * w1;
#pragma unroll
  for (int off = 32; off; off >>= 1) {
    dot += __shfl_down(dot, off);
    nw  += __shfl_down(nw, off);
  }
  if (lane == 0) {
    float s = tanhf(dot / sqrtf(nw));
    score[wid] = s;
    unsigned bb = __float_as_uint(s);
    // monotonic float->uint map (larger float -> larger uint)
    key[wid] = bb ^ ((unsigned)((int)bb >> 31) | 0x80000000u);
  }
}

// ---------------- radix select (top-k threshold), 4 passes of 8 bits --------
// rs layout (u32): [0..255]=hist, 256=prefix, 257=need, 258=cntGt, 259=cntEq
__global__ void rsel_init_kernel(unsigned* __restrict__ rs, int k) {
  int t = threadIdx.x;
  if (t < 256) rs[t] = 0u;
  if (t == 256) { rs[256] = 0u; rs[257] = (unsigned)k; rs[258] = 0u; rs[259] = 0u; }
}

__global__ void rsel_hist_kernel(const unsigned* __restrict__ key,
                                 unsigned* __restrict__ rs, int N, int shift) {
  __shared__ unsigned h[256];
  for (int i = threadIdx.x; i < 256; i += blockDim.x) h[i] = 0u;
  __syncthreads();
  unsigned prefix = rs[256];
  unsigned mask = (shift == 24) ? 0u : (0xFFFFFFFFu << (shift + 8));
  for (int i = blockIdx.x * blockDim.x + threadIdx.x; i < N; i += gridDim.x * blockDim.x) {
    unsigned kv = key[i];
    if ((kv & mask) == prefix) atomicAdd(&h[(kv >> shift) & 0xFFu], 1u);
  }
  __syncthreads();
  for (int i = threadIdx.x; i < 256; i += blockDim.x)
    if (h[i]) atomicAdd(&rs[i], h[i]);
}

__global__ void rsel_scan_kernel(unsigned* __restrict__ rs, int shift) {
  __shared__ unsigned h[256];
  int t = threadIdx.x;
  h[t] = rs[t];
  __syncthreads();
  if (t == 0) {
    unsigned need = rs[257];
    unsigned cum = 0u;
    int b = 255;
    for (; b > 0; --b) {
      unsigned c = h[b];
      if (cum + c >= need) break;
      cum += c;
    }
    rs[256] |= ((unsigned)b) << shift;
    rs[257] = need - cum;   // still needed inside bin b
  }
  __syncthreads();
  rs[t] = 0u;  // zero hist for next pass
}

__global__ void rsel_compact_kernel(const unsigned* __restrict__ key,
                                    unsigned* __restrict__ rs,
                                    int* __restrict__ perm, int N, int k) {
  unsigned T = rs[256];
  unsigned need = rs[257];
  int base = k - (int)need;  // count of keys strictly greater than T
  for (int i = blockIdx.x * blockDim.x + threadIdx.x; i < N; i += gridDim.x * blockDim.x) {
    unsigned kv = key[i];
    if (kv > T) {
      unsigned p = atomicAdd(&rs[258], 1u);
      perm[p] = i;
    } else if (kv == T) {
      unsigned t = atomicAdd(&rs[259], 1u);
      if (t < need) perm[base + (int)t] = i;
    }
  }
}

// ---------------- pool gather + gate; also gather positions ----------------
__global__ void pool_kernel(const float* __restrict__ xin, const float* __restrict__ score,
                            const int* __restrict__ perm, const float* __restrict__ posin,
                            float* __restrict__ xout, float* __restrict__ posout, int K) {
  int gid = blockIdx.x * blockDim.x + threadIdx.x;
  int i = gid >> 7, f = gid & 127;
  if (i >= K) return;
  int p = perm[i];
  float s = score[p];
  xout[(size_t)i * H + f] = xin[(size_t)p * H + f] * s;
  if (f < 2) posout[i * 2 + f] = posin[p * 2 + f];
}

// ---------------- readout: per-column max & mean over M rows ----------------
__global__ void readout_part_kernel(const float* __restrict__ x, float* __restrict__ pmax,
                                    float* __restrict__ psum, int M) {
  int f = threadIdx.x;  // 128 threads
  int rowsPer = M / gridDim.x;
  int r0 = blockIdx.x * rowsPer;
  float mx = -INFINITY, sm = 0.f;
  for (int r = r0; r < r0 + rowsPer; ++r) {
    float v = x[(size_t)r * H + f];
    mx = fmaxf(mx, v);
    sm += v;
  }
  pmax[blockIdx.x * H + f] = mx;
  psum[blockIdx.x * H + f] = sm;
}

__global__ void readout_final_kernel(const float* __restrict__ pmax,
                                     const float* __restrict__ psum,
                                     float* __restrict__ h_accum, int M, int nPart) {
  int f = threadIdx.x;  // 128 threads
  float mx = -INFINITY, sm = 0.f;
  for (int b = 0; b < nPart; ++b) {
    mx = fmaxf(mx, pmax[b * H + f]);
    sm += psum[b * H + f];
  }
  h_accum[f]     += mx;            // max goes to h[0:128]
  h_accum[H + f] += sm / (float)M; // mean goes to h[128:256]
}

// ---------------- KNN: partitioned brute force -----------------------------
// grid (M/256, KNN_P); each thread keeps a register top-K over its partition.
template<int K>
__global__ void knn_part_kernel(const float* __restrict__ pos, float* __restrict__ pd,
                                int* __restrict__ pi, int M) {
  constexpr int TILE = 1024;
  __shared__ float2 sp[TILE];
  int part = blockIdx.y;
  int i = blockIdx.x * blockDim.x + threadIdx.x;
  float2 q = reinterpret_cast<const float2*>(pos)[i];
  float bd[K];
  int   bi_[K];
#pragma unroll
  for (int j = 0; j < K; ++j) { bd[j] = INFINITY; bi_[j] = -1; }
  float worst = INFINITY;
  int plen = M / KNN_P;
  int base = part * plen;
  for (int t0 = 0; t0 < plen; t0 += TILE) {
    __syncthreads();
    for (int j = threadIdx.x; j < TILE; j += blockDim.x)
      sp[j] = reinterpret_cast<const float2*>(pos)[base + t0 + j];
    __syncthreads();
    for (int j = 0; j < TILE; ++j) {
      float dx = q.x - sp[j].x;
      float dy = q.y - sp[j].y;
      float d = dx * dx + dy * dy;
      int idx = base + t0 + j;
      if (d < worst && idx != i) {
        // find slot of current worst (constant-indexed accesses only)
        int wslot = 0; float wm = bd[0];
#pragma unroll
        for (int s = 1; s < K; ++s) if (bd[s] > wm) { wm = bd[s]; wslot = s; }
        // replace via select chain (keep arrays in registers, rule #20)
#pragma unroll
        for (int s = 0; s < K; ++s) {
          bool hit = (s == wslot);
          bd[s]  = hit ? d   : bd[s];
          bi_[s] = hit ? idx : bi_[s];
        }
        wm = bd[0];
#pragma unroll
        for (int s = 1; s < K; ++s) wm = fmaxf(wm, bd[s]);
        worst = wm;
      }
    }
  }
#pragma unroll
  for (int j = 0; j < K; ++j) {
    pd[((size_t)part * M + i) * K + j] = bd[j];
    pi[((size_t)part * M + i) * K + j] = bi_[j];
  }
}

// merge partials: one wave per query; lane l holds candidate l; K rounds of
// wave-argmin via shfl_xor butterfly (total order (d, lane) => consistent).
template<int K>
__global__ void knn_merge_kernel(const float* __restrict__ pd, const int* __restrict__ pi,
                                 int* __restrict__ nbr, int M) {
  int gid = blockIdx.x * blockDim.x + threadIdx.x;
  int wid = gid >> 6;
  int lane = threadIdx.x & 63;
  if (wid >= M) return;
  float d = INFINITY;
  int pidx = -1;
  if (lane < K * KNN_P) {
    int p = lane / K, j = lane - p * K;
    d = pd[((size_t)p * M + wid) * K + j];
    pidx = pi[((size_t)p * M + wid) * K + j];
  }
  for (int s = 0; s < K; ++s) {
    float bdv = d; int bp = pidx; int bl = lane;
#pragma unroll
    for (int off = 32; off; off >>= 1) {
      float od = __shfl_xor(bdv, off);
      int   op = __shfl_xor(bp, off);
      int   ol = __shfl_xor(bl, off);
      if (od < bdv || (od == bdv && ol < bl)) { bdv = od; bp = op; bl = ol; }
    }
    if (lane == 0) nbr[(size_t)wid * K + s] = bp;
    if (lane == bl) d = INFINITY;  // remove winner from my candidate
  }
}

// agg[i] = sum_j x[nbr[i][j]] (each dst has exactly K in-edges)
template<int K>
__global__ void knn_agg_kernel(const float* __restrict__ x, const int* __restrict__ nbr,
                               float* __restrict__ agg, int M) {
  int gid = blockIdx.x * blockDim.x + threadIdx.x;
  int i = gid >> 7, f = gid & 127;
  if (i >= M) return;
  float s = 0.f;
#pragma unroll
  for (int j = 0; j < K; ++j) s += x[(size_t)nbr[(size_t)i * K + j] * H + f];
  agg[(size_t)i * H + f] = s;
}

// ---------------- final MLP head (tiny) ------------------------------------
__global__ void mlp_kernel(const float* __restrict__ h_accum,
                           const float* __restrict__ w1, const float* __restrict__ b1,
                           const float* __restrict__ w2, const float* __restrict__ b2,
                           const float* __restrict__ w3, const float* __restrict__ b3,
                           float* __restrict__ out) {
  __shared__ float h[256], h1[128], h2[64];
  int t = threadIdx.x;
  h[t] = h_accum[t];
  __syncthreads();
  if (t < 128) {
    float a = b1[t];
    for (int c = 0; c < 256; ++c) a += h[c] * w1[c * 128 + t];
    h1[t] = fmaxf(a, 0.f);
  }
  __syncthreads();
  if (t < 64) {
    float a = b2[t];
    for (int c = 0; c < 128; ++c) a += h1[c] * w2[c * 64 + t];
    h2[t] = fmaxf(a, 0.f);
  }
  __syncthreads();
  if (t < 10) {
    float a = b3[t];
    for (int c = 0; c < 64; ++c) a += h2[c] * w3[c * 10 + t];
    out[t] = a;
  }
}

// host-side helper: issue one full top-k selection (set semantics)
void run_select(const unsigned* keys, unsigned* rs, int* perm, int N, int k,
                hipStream_t stream) {
  rsel_init_kernel<<<1, 512, 0, stream>>>(rs, k);
  const int shifts[4] = {24, 16, 8, 0};
  for (int p = 0; p < 4; ++p) {
    rsel_hist_kernel<<<256, 256, 0, stream>>>(keys, rs, N, shifts[p]);
    rsel_scan_kernel<<<1, 256, 0, stream>>>(rs, shifts[p]);
  }
  rsel_compact_kernel<<<256, 256, 0, stream>>>(keys, rs, perm, N, k);
}

}  // namespace

extern "C" void kernel_launch(void* const* d_in, const int* in_sizes, int n_in,
                              void* d_out, int out_size, void* d_ws, size_t ws_size,
                              hipStream_t stream) {
  const float* X     = (const float*)d_in[0];   // [N0, C0]
  const float* POS0  = (const float*)d_in[1];   // [N0, 2]
  const int*   EI    = (const int*)d_in[2];     // [2, E0]
  // d_in[3] = batch (unused, all zeros)
  const float* Wrel0 = (const float*)d_in[4];
  const float* brel0 = (const float*)d_in[5];
  const float* Wroot0= (const float*)d_in[6];
  const float* pw0   = (const float*)d_in[7];
  const float* Wrel1 = (const float*)d_in[8];
  const float* brel1 = (const float*)d_in[9];
  const float* Wroot1= (const float*)d_in[10];
  const float* pw1   = (const float*)d_in[11];
  const float* Wrel2 = (const float*)d_in[12];
  const float* brel2 = (const float*)d_in[13];
  const float* Wroot2= (const float*)d_in[14];
  const float* pw2   = (const float*)d_in[15];
  const float* L1W   = (const float*)d_in[16];
  const float* L1B   = (const float*)d_in[17];
  const float* L2W   = (const float*)d_in[18];
  const float* L2B   = (const float*)d_in[19];
  const float* L3W   = (const float*)d_in[20];
  const float* L3B   = (const float*)d_in[21];

  // ---- workspace layout (bytes), ~52.5 MB total, ping-pong reuse ----
  char* w = (char*)d_ws;
  float*    A   = (float*)(w);                         // 32 MB: conv outputs / knn scratch / agg
  float*    B   = (float*)(w + 33554432u);             // 16 MB: agg0 / pooled x
  float*    P1  = (float*)(w + 50331648u);             // 256 KB: pos after pool0
  float*    P2  = (float*)(w + 50593792u);             // 128 KB: pos after pool1
  int*      NBR = (int*)  (w + 50724864u);             // 768 KB: knn neighbor lists
  float*    SC  = (float*)(w + 51511296u);             // 256 KB: scores
  unsigned* KY  = (unsigned*)(w + 51773440u);          // 256 KB: radix keys
  int*      PM  = (int*)  (w + 52035584u);             // 128 KB: perm
  unsigned* RS  = (unsigned*)(w + 52166656u);          // 4 KB: radix state
  float*    RPm = (float*)(w + 52170752u);             // 128 KB: readout max partials
  float*    RPs = (float*)(w + 52301824u);             // 128 KB: readout sum partials
  float*    HA  = (float*)(w + 52432896u);             // 1 KB: h accumulator [256]

  float* OUT = (float*)d_out;

  // ==================== layer 0 ====================
  // zero agg0 and h accumulator (ws is poisoned before every timed launch)
  fill_zero_kernel<<<(N0 * C0) / 256, 256, 0, stream>>>(B, N0 * C0);
  fill_zero_kernel<<<1, 256, 0, stream>>>(HA, 256);

  // agg0 = segment_sum(x[src], dst)
  scatter_add_kernel<<<(E0 * 64) / 256, 256, 0, stream>>>(X, EI, EI + E0, B);

  // conv0_out (A) = relu(agg0@Wrel0 + brel0 + x@Wroot0)
  conv_kernel<C0, 16><<<N0 / 16, 128, 0, stream>>>(B, X, Wrel0, brel0, Wroot0, A);

  // scores + keys
  score_kernel<<<N0 / 4, 256, 0, stream>>>(A, pw0, SC, KY, N0);
  run_select(KY, RS, PM, N0, N1, stream);

  // x1 (B) = conv0_out[perm]*score[perm]; pos1 (P1) = pos0[perm]
  pool_kernel<<<(N1 * H) / 256, 256, 0, stream>>>(A, SC, PM, POS0, B, P1, N1);

  readout_part_kernel<<<256, 128, 0, stream>>>(B, RPm, RPs, N1);
  readout_final_kernel<<<1, 128, 0, stream>>>(RPm, RPs, HA, N1, 256);

  // knn on pos1 (k=6); scratch lives in A (conv0_out is dead)
  {
    float* pd = A;
    int*   pi = (int*)(A + (size_t)KNN_P * N1 * 6);
    knn_part_kernel<6><<<dim3(N1 / 256, KNN_P), 256, 0, stream>>>(P1, pd, pi, N1);
    knn_merge_kernel<6><<<N1 / 4, 256, 0, stream>>>(pd, pi, NBR, N1);
  }

  // ==================== layer 1 ====================
  float* AGG1 = A;                       // [N1, H] (overwrites knn scratch)
  float* CV1  = A + (size_t)N1 * H;      // [N1, H]
  knn_agg_kernel<6><<<(N1 * H) / 256, 256, 0, stream>>>(B, NBR, AGG1, N1);
  conv_kernel<H, 16><<<N1 / 16, 128, 0, stream>>>(AGG1, B, Wrel1, brel1, Wroot1, CV1);

  score_kernel<<<N1 / 4, 256, 0, stream>>>(CV1, pw1, SC, KY, N1);
  run_select(KY, RS, PM, N1, N2, stream);

  pool_kernel<<<(N2 * H) / 256, 256, 0, stream>>>(CV1, SC, PM, P1, B, P2, N2);

  readout_part_kernel<<<256, 128, 0, stream>>>(B, RPm, RPs, N2);
  readout_final_kernel<<<1, 128, 0, stream>>>(RPm, RPs, HA, N2, 256);

  // knn on pos2 (k=8)
  {
    float* pd = A;
    int*   pi = (int*)(A + (size_t)KNN_P * N2 * 8);
    knn_part_kernel<8><<<dim3(N2 / 256, KNN_P), 256, 0, stream>>>(P2, pd, pi, N2);
    knn_merge_kernel<8><<<N2 / 4, 256, 0, stream>>>(pd, pi, NBR, N2);
  }

  // ==================== layer 2 ====================
  float* AGG2 = A;                       // [N2, H]
  float* CV2  = A + (size_t)N2 * H;      // [N2, H]
  knn_agg_kernel<8><<<(N2 * H) / 256, 256, 0, stream>>>(B, NBR, AGG2, N2);
  conv_kernel<H, 16><<<N2 / 16, 128, 0, stream>>>(AGG2, B, Wrel2, brel2, Wroot2, CV2);

  score_kernel<<<N2 / 4, 256, 0, stream>>>(CV2, pw2, SC, KY, N2);
  run_select(KY, RS, PM, N2, N3, stream);

  // pos output of last pool is never consumed; write into P1 as scratch
  pool_kernel<<<(N3 * H) / 256, 256, 0, stream>>>(CV2, SC, PM, P2, B, P1, N3);

  readout_part_kernel<<<256, 128, 0, stream>>>(B, RPm, RPs, N3);
  readout_final_kernel<<<1, 128, 0, stream>>>(RPm, RPs, HA, N3, 256);

  // ==================== head ====================
  mlp_kernel<<<1, 256, 0, stream>>>(HA, L1W, L1B, L2W, L2B, L3W, L3B, OUT);
}

// Round 2
// 1092.919 us; speedup vs baseline: 1.7060x; 1.7060x over previous
//
#include <hip/hip_runtime.h>
#include <math.h>

// ---------------------------------------------------------------------------
// TopK graph classifier: 3x (GraphConv -> TopKPool -> readout) + 2x KNN + MLP
// N0=65536,C_IN=64,H=128,E0=524288; pooled 32768/16384/8192; knn k=6 then k=8.
// Round 2: brute-force KNN (O(M^2), ~900us+) replaced by exact uniform-grid
// KNN (counting-sort grid + ring search, ~O(M*k)).
// ---------------------------------------------------------------------------

namespace {

constexpr int N0 = 65536;
constexpr int C0 = 64;
constexpr int H  = 128;
constexpr int E0 = 524288;
constexpr int N1 = 32768;   // ceil(0.5*N0)
constexpr int N2 = 16384;
constexpr int N3 = 8192;
constexpr int G  = 64;      // knn grid dim (positions uniform in [0,1)^2)
constexpr int NC = G * G;   // 4096 cells

// ---------------- utility ----------------
__global__ void fill_zero_kernel(float* __restrict__ p, int n) {
  int i = blockIdx.x * blockDim.x + threadIdx.x;
  if (i < n) p[i] = 0.f;
}

// ---------------- conv0 aggregation: segment_sum over random edges ----------
// wave-per-edge: lane f handles feature f (C0=64 == wavefront)
__global__ void scatter_add_kernel(const float* __restrict__ x,
                                   const int* __restrict__ src,
                                   const int* __restrict__ dst,
                                   float* __restrict__ agg) {
  int gid = blockIdx.x * blockDim.x + threadIdx.x;
  int e = gid >> 6;
  int f = gid & 63;
  if (e < E0) {
    atomicAdd(&agg[(size_t)dst[e] * C0 + f], x[(size_t)src[e] * C0 + f]);
  }
}

// ---------------- graph conv: out = relu(agg@Wrel + brel + x@Wroot) ---------
template<int C, int R>
__global__ void conv_kernel(const float* __restrict__ agg,
                            const float* __restrict__ x,
                            const float* __restrict__ Wrel,
                            const float* __restrict__ brel,
                            const float* __restrict__ Wroot,
                            float* __restrict__ out) {
  __shared__ float sa[R][C];
  __shared__ float sx[R][C];
  int base = blockIdx.x * R;
  int o = threadIdx.x;  // 0..127
  for (int idx = threadIdx.x; idx < R * C; idx += 128) {
    int r = idx / C, c = idx - r * C;
    sa[r][c] = agg[(size_t)(base + r) * C + c];
    sx[r][c] = x[(size_t)(base + r) * C + c];
  }
  __syncthreads();
  float acc[R];
  float b = brel[o];
#pragma unroll
  for (int r = 0; r < R; ++r) acc[r] = b;
  for (int c = 0; c < C; ++c) {
    float wr = Wrel[c * H + o];
    float wo = Wroot[c * H + o];
#pragma unroll
    for (int r = 0; r < R; ++r) acc[r] += sa[r][c] * wr + sx[r][c] * wo;
  }
#pragma unroll
  for (int r = 0; r < R; ++r) out[(size_t)(base + r) * H + o] = fmaxf(acc[r], 0.f);
}

// ---------------- pooling scores: tanh(x.pw/||pw||), + radix-sortable key ---
__global__ void score_kernel(const float* __restrict__ xin,
                             const float* __restrict__ pw,
                             float* __restrict__ score,
                             unsigned* __restrict__ key, int N) {
  int gid = blockIdx.x * blockDim.x + threadIdx.x;
  int wid = gid >> 6;
  int lane = threadIdx.x & 63;
  if (wid >= N) return;
  float w0 = pw[lane], w1 = pw[64 + lane];
  float x0 = xin[(size_t)wid * H + lane], x1 = xin[(size_t)wid * H + 64 + lane];
  float dot = x0 * w0 + x1 * w1;
  float nw = w0 * w0 + w1 * w1;
#pragma unroll
  for (int off = 32; off; off >>= 1) {
    dot += __shfl_down(dot, off);
    nw  += __shfl_down(nw, off);
  }
  if (lane == 0) {
    float s = tanhf(dot / sqrtf(nw));
    score[wid] = s;
    unsigned bb = __float_as_uint(s);
    key[wid] = bb ^ ((unsigned)((int)bb >> 31) | 0x80000000u);
  }
}

// ---------------- radix select (top-k threshold), 4 passes of 8 bits --------
__global__ void rsel_init_kernel(unsigned* __restrict__ rs, int k) {
  int t = threadIdx.x;
  if (t < 256) rs[t] = 0u;
  if (t == 256) { rs[256] = 0u; rs[257] = (unsigned)k; rs[258] = 0u; rs[259] = 0u; }
}

__global__ void rsel_hist_kernel(const unsigned* __restrict__ key,
                                 unsigned* __restrict__ rs, int N, int shift) {
  __shared__ unsigned h[256];
  for (int i = threadIdx.x; i < 256; i += blockDim.x) h[i] = 0u;
  __syncthreads();
  unsigned prefix = rs[256];
  unsigned mask = (shift == 24) ? 0u : (0xFFFFFFFFu << (shift + 8));
  for (int i = blockIdx.x * blockDim.x + threadIdx.x; i < N; i += gridDim.x * blockDim.x) {
    unsigned kv = key[i];
    if ((kv & mask) == prefix) atomicAdd(&h[(kv >> shift) & 0xFFu], 1u);
  }
  __syncthreads();
  for (int i = threadIdx.x; i < 256; i += blockDim.x)
    if (h[i]) atomicAdd(&rs[i], h[i]);
}

__global__ void rsel_scan_kernel(unsigned* __restrict__ rs, int shift) {
  __shared__ unsigned h[256];
  int t = threadIdx.x;
  h[t] = rs[t];
  __syncthreads();
  if (t == 0) {
    unsigned need = rs[257];
    unsigned cum = 0u;
    int b = 255;
    for (; b > 0; --b) {
      unsigned c = h[b];
      if (cum + c >= need) break;
      cum += c;
    }
    rs[256] |= ((unsigned)b) << shift;
    rs[257] = need - cum;
  }
  __syncthreads();
  rs[t] = 0u;
}

__global__ void rsel_compact_kernel(const unsigned* __restrict__ key,
                                    unsigned* __restrict__ rs,
                                    int* __restrict__ perm, int N, int k) {
  unsigned T = rs[256];
  unsigned need = rs[257];
  int base = k - (int)need;
  for (int i = blockIdx.x * blockDim.x + threadIdx.x; i < N; i += gridDim.x * blockDim.x) {
    unsigned kv = key[i];
    if (kv > T) {
      unsigned p = atomicAdd(&rs[258], 1u);
      perm[p] = i;
    } else if (kv == T) {
      unsigned t = atomicAdd(&rs[259], 1u);
      if (t < need) perm[base + (int)t] = i;
    }
  }
}

// ---------------- pool gather + gate; also gather positions ----------------
__global__ void pool_kernel(const float* __restrict__ xin, const float* __restrict__ score,
                            const int* __restrict__ perm, const float* __restrict__ posin,
                            float* __restrict__ xout, float* __restrict__ posout, int K) {
  int gid = blockIdx.x * blockDim.x + threadIdx.x;
  int i = gid >> 7, f = gid & 127;
  if (i >= K) return;
  int p = perm[i];
  float s = score[p];
  xout[(size_t)i * H + f] = xin[(size_t)p * H + f] * s;
  if (f < 2) posout[i * 2 + f] = posin[p * 2 + f];
}

// ---------------- readout: per-column max & mean over M rows ----------------
__global__ void readout_part_kernel(const float* __restrict__ x, float* __restrict__ pmax,
                                    float* __restrict__ psum, int M) {
  int f = threadIdx.x;  // 128 threads
  int rowsPer = M / gridDim.x;
  int r0 = blockIdx.x * rowsPer;
  float mx = -INFINITY, sm = 0.f;
  for (int r = r0; r < r0 + rowsPer; ++r) {
    float v = x[(size_t)r * H + f];
    mx = fmaxf(mx, v);
    sm += v;
  }
  pmax[blockIdx.x * H + f] = mx;
  psum[blockIdx.x * H + f] = sm;
}

__global__ void readout_final_kernel(const float* __restrict__ pmax,
                                     const float* __restrict__ psum,
                                     float* __restrict__ h_accum, int M, int nPart) {
  int f = threadIdx.x;  // 128 threads
  float mx = -INFINITY, sm = 0.f;
  for (int b = 0; b < nPart; ++b) {
    mx = fmaxf(mx, pmax[b * H + f]);
    sm += psum[b * H + f];
  }
  h_accum[f]     += mx;
  h_accum[H + f] += sm / (float)M;
}

// ---------------- KNN via uniform grid (exact) -----------------------------
// positions are uniform in [0,1)^2; 64x64 grid, counting-sort into cell lists,
// then per-query expanding ring search with an exact termination bound.

__global__ void grid_assign_kernel(const float* __restrict__ pos,
                                   unsigned* __restrict__ cnt,
                                   int* __restrict__ cellId, int M) {
  int i = blockIdx.x * blockDim.x + threadIdx.x;
  if (i >= M) return;
  float2 p = reinterpret_cast<const float2*>(pos)[i];
  int cx = min(max((int)(p.x * (float)G), 0), G - 1);
  int cy = min(max((int)(p.y * (float)G), 0), G - 1);
  int c = cy * G + cx;
  cellId[i] = c;
  atomicAdd(&cnt[c], 1u);
}

// exclusive prefix over NC=4096 cells; one block of 1024 threads, 4 per thread
__global__ void grid_scan_kernel(const unsigned* __restrict__ cnt,
                                 unsigned* __restrict__ pre,
                                 unsigned* __restrict__ cursor) {
  __shared__ unsigned s[1024];
  int t = threadIdx.x;
  unsigned v0 = cnt[4 * t], v1 = cnt[4 * t + 1], v2 = cnt[4 * t + 2], v3 = cnt[4 * t + 3];
  unsigned tsum = v0 + v1 + v2 + v3;
  s[t] = tsum;
  __syncthreads();
  for (int off = 1; off < 1024; off <<= 1) {
    unsigned x = (t >= off) ? s[t - off] : 0u;
    __syncthreads();
    s[t] += x;
    __syncthreads();
  }
  unsigned excl = s[t] - tsum;
  unsigned p0 = excl, p1 = excl + v0, p2 = p1 + v1, p3 = p2 + v2;
  pre[4 * t] = p0; pre[4 * t + 1] = p1; pre[4 * t + 2] = p2; pre[4 * t + 3] = p3;
  cursor[4 * t] = p0; cursor[4 * t + 1] = p1; cursor[4 * t + 2] = p2; cursor[4 * t + 3] = p3;
  if (t == 1023) pre[NC] = p3 + v3;
}

__global__ void grid_scatter_kernel(const int* __restrict__ cellId,
                                    unsigned* __restrict__ cursor,
                                    int* __restrict__ cellPts, int M) {
  int i = blockIdx.x * blockDim.x + threadIdx.x;
  if (i >= M) return;
  unsigned slot = atomicAdd(&cursor[cellId[i]], 1u);
  cellPts[slot] = i;
}

// one thread per query; register top-K (constant-indexed only); exact stop:
// after rings 0..r-1 the unvisited region is outside the (2r-1)^2 cell box,
// whose min distance to q is m; stop when worst (=max of full list) <= m^2.
template<int K>
__global__ void knn_grid_kernel(const float* __restrict__ pos,
                                const unsigned* __restrict__ pre,
                                const int* __restrict__ cellPts,
                                int* __restrict__ nbr, int M) {
  int i = blockIdx.x * blockDim.x + threadIdx.x;
  if (i >= M) return;
  float2 q = reinterpret_cast<const float2*>(pos)[i];
  int cx = min(max((int)(q.x * (float)G), 0), G - 1);
  int cy = min(max((int)(q.y * (float)G), 0), G - 1);
  float bd[K];
  int   bi_[K];
#pragma unroll
  for (int t = 0; t < K; ++t) { bd[t] = INFINITY; bi_[t] = -1; }
  float worst = INFINITY;  // stays INF until list is full (empties are INF)
  constexpr float cw = 1.0f / (float)G;
  for (int r = 0; r <= G; ++r) {
    if (r > 0) {
      float dl = q.x - (float)(cx - r + 1) * cw;
      float dr = (float)(cx + r) * cw - q.x;
      float db = q.y - (float)(cy - r + 1) * cw;
      float dt = (float)(cy + r) * cw - q.y;
      float m = fminf(fminf(dl, dr), fminf(db, dt));
      if (worst <= m * m) break;   // exact: no unvisited point can beat worst
    }
    int xlo = max(cx - r, 0), xhi = min(cx + r, G - 1);
    int ylo = max(cy - r, 0), yhi = min(cy + r, G - 1);
    for (int yy = ylo; yy <= yhi; ++yy) {
      bool yedge = (yy == cy - r) || (yy == cy + r);
      for (int xx = xlo; xx <= xhi; ++xx) {
        if (!yedge && xx != cx - r && xx != cx + r) continue;  // ring only
        int c = yy * G + xx;
        unsigned s0 = pre[c], s1 = pre[c + 1];
        for (unsigned s = s0; s < s1; ++s) {
          int j = cellPts[s];
          float2 pj = reinterpret_cast<const float2*>(pos)[j];
          float dx = q.x - pj.x, dy = q.y - pj.y;
          float d = dx * dx + dy * dy;
          if (d < worst && j != i) {
            int ws = 0; float wm = bd[0];
#pragma unroll
            for (int t = 1; t < K; ++t) if (bd[t] > wm) { wm = bd[t]; ws = t; }
#pragma unroll
            for (int t = 0; t < K; ++t) {
              bool hit = (t == ws);
              bd[t]  = hit ? d : bd[t];
              bi_[t] = hit ? j : bi_[t];
            }
            float nm = bd[0];
#pragma unroll
            for (int t = 1; t < K; ++t) nm = fmaxf(nm, bd[t]);
            worst = nm;
          }
        }
      }
    }
  }
#pragma unroll
  for (int t = 0; t < K; ++t) nbr[(size_t)i * K + t] = bi_[t];
}

// agg[i] = sum_j x[nbr[i][j]] (each dst has exactly K in-edges)
template<int K>
__global__ void knn_agg_kernel(const float* __restrict__ x, const int* __restrict__ nbr,
                               float* __restrict__ agg, int M) {
  int gid = blockIdx.x * blockDim.x + threadIdx.x;
  int i = gid >> 7, f = gid & 127;
  if (i >= M) return;
  float s = 0.f;
#pragma unroll
  for (int j = 0; j < K; ++j) s += x[(size_t)nbr[(size_t)i * K + j] * H + f];
  agg[(size_t)i * H + f] = s;
}

// ---------------- final MLP head (tiny) ------------------------------------
__global__ void mlp_kernel(const float* __restrict__ h_accum,
                           const float* __restrict__ w1, const float* __restrict__ b1,
                           const float* __restrict__ w2, const float* __restrict__ b2,
                           const float* __restrict__ w3, const float* __restrict__ b3,
                           float* __restrict__ out) {
  __shared__ float h[256], h1[128], h2[64];
  int t = threadIdx.x;
  h[t] = h_accum[t];
  __syncthreads();
  if (t < 128) {
    float a = b1[t];
    for (int c = 0; c < 256; ++c) a += h[c] * w1[c * 128 + t];
    h1[t] = fmaxf(a, 0.f);
  }
  __syncthreads();
  if (t < 64) {
    float a = b2[t];
    for (int c = 0; c < 128; ++c) a += h1[c] * w2[c * 64 + t];
    h2[t] = fmaxf(a, 0.f);
  }
  __syncthreads();
  if (t < 10) {
    float a = b3[t];
    for (int c = 0; c < 64; ++c) a += h2[c] * w3[c * 10 + t];
    out[t] = a;
  }
}

// host-side helper: one full top-k selection (set semantics)
void run_select(const unsigned* keys, unsigned* rs, int* perm, int N, int k,
                hipStream_t stream) {
  rsel_init_kernel<<<1, 512, 0, stream>>>(rs, k);
  const int shifts[4] = {24, 16, 8, 0};
  for (int p = 0; p < 4; ++p) {
    rsel_hist_kernel<<<256, 256, 0, stream>>>(keys, rs, N, shifts[p]);
    rsel_scan_kernel<<<1, 256, 0, stream>>>(rs, shifts[p]);
  }
  rsel_compact_kernel<<<256, 256, 0, stream>>>(keys, rs, perm, N, k);
}

// host-side helper: grid-based exact KNN, writes nbr[M*K]
template<int K>
void run_knn(const float* posM, int M, char* scratch, int* nbr, hipStream_t stream) {
  unsigned* cnt   = (unsigned*)(scratch);                 // [NC]
  unsigned* pre   = (unsigned*)(scratch + 16384);         // [NC+1]
  unsigned* cur   = (unsigned*)(scratch + 32768 + 4096);  // [NC]
  int*      cid   = (int*)     (scratch + 65536);         // [M]
  int*      cpts  = (int*)     (scratch + 65536 + 131072);// [M]
  fill_zero_kernel<<<NC / 256, 256, 0, stream>>>((float*)cnt, NC);
  grid_assign_kernel<<<M / 256, 256, 0, stream>>>(posM, cnt, cid, M);
  grid_scan_kernel<<<1, 1024, 0, stream>>>(cnt, pre, cur);
  grid_scatter_kernel<<<M / 256, 256, 0, stream>>>(cid, cur, cpts, M);
  knn_grid_kernel<K><<<M / 256, 256, 0, stream>>>(posM, pre, cpts, nbr, M);
}

}  // namespace

extern "C" void kernel_launch(void* const* d_in, const int* in_sizes, int n_in,
                              void* d_out, int out_size, void* d_ws, size_t ws_size,
                              hipStream_t stream) {
  const float* X     = (const float*)d_in[0];   // [N0, C0]
  const float* POS0  = (const float*)d_in[1];   // [N0, 2]
  const int*   EI    = (const int*)d_in[2];     // [2, E0]
  const float* Wrel0 = (const float*)d_in[4];
  const float* brel0 = (const float*)d_in[5];
  const float* Wroot0= (const float*)d_in[6];
  const float* pw0   = (const float*)d_in[7];
  const float* Wrel1 = (const float*)d_in[8];
  const float* brel1 = (const float*)d_in[9];
  const float* Wroot1= (const float*)d_in[10];
  const float* pw1   = (const float*)d_in[11];
  const float* Wrel2 = (const float*)d_in[12];
  const float* brel2 = (const float*)d_in[13];
  const float* Wroot2= (const float*)d_in[14];
  const float* pw2   = (const float*)d_in[15];
  const float* L1W   = (const float*)d_in[16];
  const float* L1B   = (const float*)d_in[17];
  const float* L2W   = (const float*)d_in[18];
  const float* L2B   = (const float*)d_in[19];
  const float* L3W   = (const float*)d_in[20];
  const float* L3B   = (const float*)d_in[21];

  // ---- workspace layout (bytes), ping-pong reuse ----
  char* w = (char*)d_ws;
  float*    A   = (float*)(w);                         // 32 MB: conv outputs / knn scratch / agg
  float*    B   = (float*)(w + 33554432u);             // 16 MB: agg0 / pooled x
  float*    P1  = (float*)(w + 50331648u);             // 256 KB: pos after pool0
  float*    P2  = (float*)(w + 50593792u);             // 128 KB: pos after pool1
  int*      NBR = (int*)  (w + 50724864u);             // 768 KB: knn neighbor lists
  float*    SC  = (float*)(w + 51511296u);             // 256 KB: scores
  unsigned* KY  = (unsigned*)(w + 51773440u);          // 256 KB: radix keys
  int*      PM  = (int*)  (w + 52035584u);             // 128 KB: perm
  unsigned* RS  = (unsigned*)(w + 52166656u);          // 4 KB: radix state
  float*    RPm = (float*)(w + 52170752u);             // 128 KB: readout max partials
  float*    RPs = (float*)(w + 52301824u);             // 128 KB: readout sum partials
  float*    HA  = (float*)(w + 52432896u);             // 1 KB: h accumulator [256]

  float* OUT = (float*)d_out;

  // ==================== layer 0 ====================
  fill_zero_kernel<<<(N0 * C0) / 256, 256, 0, stream>>>(B, N0 * C0);
  fill_zero_kernel<<<1, 256, 0, stream>>>(HA, 256);

  scatter_add_kernel<<<(E0 * 64) / 256, 256, 0, stream>>>(X, EI, EI + E0, B);

  conv_kernel<C0, 16><<<N0 / 16, 128, 0, stream>>>(B, X, Wrel0, brel0, Wroot0, A);

  score_kernel<<<N0 / 4, 256, 0, stream>>>(A, pw0, SC, KY, N0);
  run_select(KY, RS, PM, N0, N1, stream);

  pool_kernel<<<(N1 * H) / 256, 256, 0, stream>>>(A, SC, PM, POS0, B, P1, N1);

  readout_part_kernel<<<256, 128, 0, stream>>>(B, RPm, RPs, N1);
  readout_final_kernel<<<1, 128, 0, stream>>>(RPm, RPs, HA, N1, 256);

  // knn on pos1 (k=6); grid scratch in A (conv0_out is dead)
  run_knn<6>(P1, N1, (char*)A, NBR, stream);

  // ==================== layer 1 ====================
  float* AGG1 = A;                       // [N1, H] (overwrites knn scratch)
  float* CV1  = A + (size_t)N1 * H;      // [N1, H]
  knn_agg_kernel<6><<<(N1 * H) / 256, 256, 0, stream>>>(B, NBR, AGG1, N1);
  conv_kernel<H, 16><<<N1 / 16, 128, 0, stream>>>(AGG1, B, Wrel1, brel1, Wroot1, CV1);

  score_kernel<<<N1 / 4, 256, 0, stream>>>(CV1, pw1, SC, KY, N1);
  run_select(KY, RS, PM, N1, N2, stream);

  pool_kernel<<<(N2 * H) / 256, 256, 0, stream>>>(CV1, SC, PM, P1, B, P2, N2);

  readout_part_kernel<<<256, 128, 0, stream>>>(B, RPm, RPs, N2);
  readout_final_kernel<<<1, 128, 0, stream>>>(RPm, RPs, HA, N2, 256);

  // knn on pos2 (k=8)
  run_knn<8>(P2, N2, (char*)A, NBR, stream);

  // ==================== layer 2 ====================
  float* AGG2 = A;                       // [N2, H]
  float* CV2  = A + (size_t)N2 * H;      // [N2, H]
  knn_agg_kernel<8><<<(N2 * H) / 256, 256, 0, stream>>>(B, NBR, AGG2, N2);
  conv_kernel<H, 16><<<N2 / 16, 128, 0, stream>>>(AGG2, B, Wrel2, brel2, Wroot2, CV2);

  score_kernel<<<N2 / 4, 256, 0, stream>>>(CV2, pw2, SC, KY, N2);
  run_select(KY, RS, PM, N2, N3, stream);

  pool_kernel<<<(N3 * H) / 256, 256, 0, stream>>>(CV2, SC, PM, P2, B, P1, N3);

  readout_part_kernel<<<256, 128, 0, stream>>>(B, RPm, RPs, N3);
  readout_final_kernel<<<1, 128, 0, stream>>>(RPm, RPs, HA, N3, 256);

  // ==================== head ====================
  mlp_kernel<<<1, 256, 0, stream>>>(HA, L1W, L1B, L2W, L2B, L3W, L3B, OUT);
}